// Round 1
// baseline (443.939 us; speedup 1.0000x reference)
//
#include <hip/hip_runtime.h>

// ALiBi bias add for (1, 16, 4096, 4096) fp32 scores.
// out[i] = in[i] + (k - 4095) * 2^(-0.5*(h+1)),
//   h = (i >> 24) & 15   (4096*4096 = 2^24 elements per head)
//   k = i & 4095         (key_len = 4096)
// Memory-bound elementwise: float4 loads/stores, grid-stride loop.

__global__ void alibi_add_kernel(const float* __restrict__ in,
                                 float* __restrict__ out,
                                 long long n4) {
    long long idx    = (long long)blockIdx.x * blockDim.x + threadIdx.x;
    long long stride = (long long)gridDim.x * blockDim.x;
    for (long long j = idx; j < n4; j += stride) {
        long long i = j << 2;                      // element index of .x
        int h = (int)((i >> 24) & 15);
        int k = (int)(i & 4095);
        float slope = exp2f(-0.5f * (float)(h + 1));
        float d0 = (float)(k - 4095);

        float4 v = reinterpret_cast<const float4*>(in)[j];
        v.x += d0 * slope;
        v.y += (d0 + 1.0f) * slope;
        v.z += (d0 + 2.0f) * slope;
        v.w += (d0 + 3.0f) * slope;
        reinterpret_cast<float4*>(out)[j] = v;
    }
}

extern "C" void kernel_launch(void* const* d_in, const int* in_sizes, int n_in,
                              void* d_out, int out_size, void* d_ws, size_t ws_size,
                              hipStream_t stream) {
    const float* in = (const float*)d_in[0];
    float* out = (float*)d_out;

    long long n4 = (long long)out_size / 4;        // 2^26 float4s
    const int block = 256;
    // Cap grid at 8 blocks/CU * 256 CUs; grid-stride covers the rest.
    long long blocks_needed = (n4 + block - 1) / block;
    int grid = (int)(blocks_needed < 2048 ? blocks_needed : 2048);

    alibi_add_kernel<<<grid, block, 0, stream>>>(in, out, n4);
}

// Round 2
// 393.316 us; speedup vs baseline: 1.1287x; 1.1287x over previous
//
#include <hip/hip_runtime.h>

// ALiBi bias add for (1, 16, 4096, 4096) fp32 scores.
// out[i] = in[i] + (k - 4095) * 2^(-0.5*(h+1)),
//   h = (i >> 24) & 15   (4096*4096 = 2^24 elements per head)
//   k = i & 4095         (key_len = 4096)
//
// Memory-bound. Round-1 lesson: grid-stride with 1 load+1 store per
// iteration serializes on vmcnt (store shares the counter) -> ~1
// outstanding load/wave -> 4.84 TB/s. Fix: 8 float4s per thread, all
// loads issued before any use (ILP=8). Block covers 8192 consecutive
// elements = inside one head -> slope is block-uniform (SGPR + one exp2f).

constexpr int U = 8;            // float4s per thread
constexpr int BLOCK = 256;
// elements per block = BLOCK * U * 4 = 8192  (divides 2^24 per-head span)

__global__ void alibi_add_kernel(const float4* __restrict__ in,
                                 float4* __restrict__ out) {
    // float4 index of this thread's first chunk
    long long base = (long long)blockIdx.x * (BLOCK * U) + threadIdx.x;

    // head is uniform across the block (8192 elems per block, 2^24 per head)
    int h = (int)((((long long)blockIdx.x * (BLOCK * U * 4)) >> 24) & 15);
    float slope = exp2f(-0.5f * (float)(h + 1));

    float4 v[U];
#pragma unroll
    for (int u = 0; u < U; ++u)
        v[u] = in[base + u * BLOCK];

#pragma unroll
    for (int u = 0; u < U; ++u) {
        long long i = (base + u * BLOCK) << 2;     // element index of .x
        float d0 = (float)((int)(i & 4095) - 4095);
        v[u].x += d0 * slope;
        v[u].y += (d0 + 1.0f) * slope;
        v[u].z += (d0 + 2.0f) * slope;
        v[u].w += (d0 + 3.0f) * slope;
        out[base + u * BLOCK] = v[u];
    }
}

extern "C" void kernel_launch(void* const* d_in, const int* in_sizes, int n_in,
                              void* d_out, int out_size, void* d_ws, size_t ws_size,
                              hipStream_t stream) {
    const float4* in = (const float4*)d_in[0];
    float4* out = (float4*)d_out;

    long long n4 = (long long)out_size / 4;              // 2^26 float4s
    long long grid = n4 / (BLOCK * U);                   // 32768, exact
    alibi_add_kernel<<<(int)grid, BLOCK, 0, stream>>>(in, out);
}

// Round 4
// 384.513 us; speedup vs baseline: 1.1546x; 1.0229x over previous
//
#include <hip/hip_runtime.h>

// ALiBi bias add for (1, 16, 4096, 4096) fp32 scores.
// out[i] = in[i] + (k - 4095) * 2^(-0.5*(h+1)),
//   h = (i >> 24) & 15, k = i & 4095.
//
// R1: grid-stride 1-load-in-flight -> 4.84 TB/s (latency-bound).
// R2: ILP=8, one-shot threads -> 5.46 TB/s (87% of copy ceiling).
// R3: ILP=16 (256 B/thread) + nontemporal loads/stores.
//     NB: __builtin_nontemporal_* needs a NATIVE vector type, not
//     HIP_vector_type<float,4> -> use ext_vector_type(4) float.

typedef float f4 __attribute__((ext_vector_type(4)));

constexpr int U = 16;           // f4 chunks per thread
constexpr int BLOCK = 256;
// elements per block = BLOCK * U * 4 = 16384 (divides 2^24 per-head span,
// so the head index -> slope is block-uniform)

__global__ void alibi_add_kernel(const f4* __restrict__ in,
                                 f4* __restrict__ out) {
    long long base = (long long)blockIdx.x * (BLOCK * U) + threadIdx.x;

    int h = (int)((((long long)blockIdx.x * (BLOCK * U * 4)) >> 24) & 15);
    float slope = exp2f(-0.5f * (float)(h + 1));

    f4 v[U];
#pragma unroll
    for (int u = 0; u < U; ++u)
        v[u] = __builtin_nontemporal_load(&in[base + u * BLOCK]);

#pragma unroll
    for (int u = 0; u < U; ++u) {
        long long i = (base + u * BLOCK) << 2;     // element index of .x
        float d0 = (float)((int)(i & 4095) - 4095);
        v[u].x += d0 * slope;
        v[u].y += (d0 + 1.0f) * slope;
        v[u].z += (d0 + 2.0f) * slope;
        v[u].w += (d0 + 3.0f) * slope;
        __builtin_nontemporal_store(v[u], &out[base + u * BLOCK]);
    }
}

extern "C" void kernel_launch(void* const* d_in, const int* in_sizes, int n_in,
                              void* d_out, int out_size, void* d_ws, size_t ws_size,
                              hipStream_t stream) {
    const f4* in = (const f4*)d_in[0];
    f4* out = (f4*)d_out;

    long long n4 = (long long)out_size / 4;              // 2^26 f4 chunks
    long long grid = n4 / (BLOCK * U);                   // 16384, exact
    alibi_add_kernel<<<(int)grid, BLOCK, 0, stream>>>(in, out);
}

// Round 5
// 349.596 us; speedup vs baseline: 1.2699x; 1.0999x over previous
//
#include <hip/hip_runtime.h>

// ALiBi bias add for (1, 16, 4096, 4096) fp32 scores.
// out[i] = in[i] + (k - 4095) * 2^(-0.5*(h+1)),
//   h = (i >> 24) & 15, k = i & 4095.
//
// R1: grid-stride, 1 load in flight -> 4.84 TB/s (latency-bound).
// R2: ILP=8 one-shot threads        -> 5.46 TB/s.
// R4: ILP=16 + nontemporal          -> 5.59 TB/s (89% of copy ceiling).
// R5: occupancy experiment — U=8 + __launch_bounds__(256,8) caps VGPR<=64
//     -> 8 waves/SIMD (2x R4). Decides occupancy-vs-BW-ceiling.
//     32-bit indices (j < 2^26) to trim addressing VALU.

typedef float f4 __attribute__((ext_vector_type(4)));

constexpr int U = 8;            // f4 chunks per thread
constexpr int BLOCK = 256;
// elems per block = BLOCK*U*4 = 8192 -> head (and slope) block-uniform,
// and blockIdx>>11 gives the head directly (8192*2048 = 2^24).

__global__ void __launch_bounds__(BLOCK, 8)
alibi_add_kernel(const f4* __restrict__ in, f4* __restrict__ out) {
    unsigned j0 = blockIdx.x * (BLOCK * U) + threadIdx.x;   // f4 index < 2^26

    int h = (int)(blockIdx.x >> 11);                        // block-uniform
    float slope = exp2f(-0.5f * (float)(h + 1));

    f4 v[U];
#pragma unroll
    for (int u = 0; u < U; ++u)
        v[u] = __builtin_nontemporal_load(&in[j0 + u * BLOCK]);

#pragma unroll
    for (int u = 0; u < U; ++u) {
        unsigned j = j0 + u * BLOCK;
        // element index i = 4*j; k = i & 4095 = (j & 1023) * 4
        float d0 = (float)((int)((j & 1023u) << 2) - 4095);
        v[u].x += d0 * slope;
        v[u].y += (d0 + 1.0f) * slope;
        v[u].z += (d0 + 2.0f) * slope;
        v[u].w += (d0 + 3.0f) * slope;
        __builtin_nontemporal_store(v[u], &out[j]);
    }
}

extern "C" void kernel_launch(void* const* d_in, const int* in_sizes, int n_in,
                              void* d_out, int out_size, void* d_ws, size_t ws_size,
                              hipStream_t stream) {
    const f4* in = (const f4*)d_in[0];
    f4* out = (f4*)d_out;

    long long n4 = (long long)out_size / 4;              // 2^26 f4 chunks
    long long grid = n4 / (BLOCK * U);                   // 32768, exact
    alibi_add_kernel<<<(int)grid, BLOCK, 0, stream>>>(in, out);
}